// Round 12
// baseline (356.049 us; speedup 1.0000x reference)
//
#include <hip/hip_runtime.h>

typedef int v4i __attribute__((ext_vector_type(4)));

#define MM 8192
#define KK 4096
#define NN 4096
#define NG 8
#define NKT 64                   // K / 64
#define FRAG_BYTES 1024          // one MFMA fragment: 16 rows x 64 k, lane-major
#define FROW_BYTES (NKT * FRAG_BYTES)        // 64 KB: one frag-row, all kt
#define A_FRAGS 512              // M / 16
#define B_FRAGS_PER_G 256        // N / 16
#define AP_BYTES ((size_t)A_FRAGS * FROW_BYTES)               // 32 MB
#define BP_BYTES ((size_t)NG * B_FRAGS_PER_G * FROW_BYTES)    // 128 MB

#define BM 256
#define BN 256

// XOR swizzle (fallback kernel only)
__device__ __forceinline__ int swz(int row, int c) {
    int line = row >> 1;
    int s = ((((row & 1) << 2) | (c >> 4)) ^ ((row >> 2) & 7));
    return line * 128 + s * 16 + (c & 15);
}

__device__ __forceinline__ unsigned pack4(v4i v) {
    return (v.x & 255) | ((v.y & 255) << 8) | ((v.z & 255) << 16) |
           ((unsigned)v.w << 24);
}

// ---- pack A (R8-verified): int32 [M][K] -> int8 fragment-major:
// frag (mi, kt) at (mi*64+kt)*1024; byte l*16+j = A[mi*16+(l&15)][kt*64+(l>>4)*16+j]
__global__ __launch_bounds__(256)
void pack_a(const int* __restrict__ A, unsigned char* __restrict__ Ap)
{
    const int mi  = blockIdx.x;          // 0..511
    const int t   = threadIdx.x;
    const int l   = t & 63;
    const int kt4 = t >> 6;              // 0..3
    const int row = mi * 16 + (l & 15);
    const int kc  = (l >> 4) * 16;
    const int* src0 = A + (size_t)row * KK + kc;
    unsigned char* dst0 = Ap + (size_t)mi * FROW_BYTES + l * 16;

    #pragma unroll
    for (int j = 0; j < 16; ++j) {
        const int kt = kt4 * 16 + j;
        const int* src = src0 + kt * 64;
        v4i x0 = ((const v4i*)src)[0];
        v4i x1 = ((const v4i*)src)[1];
        v4i x2 = ((const v4i*)src)[2];
        v4i x3 = ((const v4i*)src)[3];
        v4i w;
        w.x = (int)pack4(x0); w.y = (int)pack4(x1);
        w.z = (int)pack4(x2); w.w = (int)pack4(x3);
        *(v4i*)(dst0 + (size_t)kt * FRAG_BYTES) = w;
    }
}

// ---- pack B: int32 [G][K][N] -> int8 fragment-major:
// frag (g, n16, kt) at ((g*256+n16)*64+kt)*1024;
// byte l*16+j = B[g][kt*64+(l>>4)*16+j][n16*16+(l&15)]
// (mirrors verified pack_b v1 mechanics: 8 coalesced reads + 8B writes)
__global__ __launch_bounds__(256)
void pack_b(const int* __restrict__ B, unsigned char* __restrict__ Bp)
{
    const int b    = blockIdx.x;
    const int g    = b >> 11;
    const int n128 = (b >> 6) & 31;      // 128-col slab
    const int kt   = b & 63;
    const int t    = threadIdx.x;
    const int k0   = (t >> 5) * 8;       // 8 consecutive k
    const int n4   = (t & 31) * 4;       // 4 consecutive n (0..127)

    const int* src = B + (size_t)g * KK * NN + (size_t)(kt * 64 + k0) * NN
                       + n128 * 128 + n4;
    v4i r[8];
    #pragma unroll
    for (int j = 0; j < 8; ++j)
        r[j] = *(const v4i*)(src + (size_t)j * NN);

    unsigned char* dstg = Bp + ((size_t)(g * B_FRAGS_PER_G + n128 * 8) * NKT + kt)
                              * FRAG_BYTES;
    #pragma unroll
    for (int n = 0; n < 4; ++n) {
        const int col  = n4 + n;             // 0..127
        const int f    = col >> 4;           // frag within slab
        const int lane = (col & 15) + ((k0 >> 4) << 4);
        unsigned lo = (r[0][n] & 255) | ((r[1][n] & 255) << 8) |
                      ((r[2][n] & 255) << 16) | ((unsigned)r[3][n] << 24);
        unsigned hi = (r[4][n] & 255) | ((r[5][n] & 255) << 8) |
                      ((r[6][n] & 255) << 16) | ((unsigned)r[7][n] << 24);
        unsigned long long wv = (unsigned long long)lo |
                                ((unsigned long long)hi << 32);
        *(unsigned long long*)(dstg + (size_t)f * FROW_BYTES
                               + lane * 16 + (k0 & 15)) = wv;
    }
}

// One K-step: prefetch next kt's fragments into AFN/BFN, MFMA current.
#define KSTEP(AFC, BFC, AFN, BFN, OFF, DO_PF)                              \
    do {                                                                   \
        if (DO_PF) {                                                       \
            _Pragma("unroll") for (int n = 0; n < 4; ++n)                  \
                BFN[n] = *(const v4i*)(bbase + boff[n] + (OFF));           \
            _Pragma("unroll") for (int m = 0; m < 8; ++m)                  \
                AFN[m] = *(const v4i*)(abase + aoff[m] + (OFF));           \
        }                                                                  \
        __builtin_amdgcn_s_setprio(1);                                     \
        _Pragma("unroll") for (int m = 0; m < 8; ++m)                      \
            _Pragma("unroll") for (int n = 0; n < 4; ++n)                  \
                acc[m][n] = __builtin_amdgcn_mfma_i32_16x16x64_i8(         \
                    AFC[m], BFC[n], acc[m][n], 0, 0, 0);                   \
        __builtin_amdgcn_s_setprio(0);                                     \
    } while (0)

// ---- main GEMM: 256x256, 8 waves, NO LDS, NO barriers. Both operands
// fragment-major in global; each fragment load = 64 lanes x contiguous 16B
// (one coalesced 1KB burst). Waves free-run on compiler-counted vmcnt with
// register double-buffering. ----
__global__ __launch_bounds__(512, 2)
void gg_i8r(const unsigned char* __restrict__ Ap,
            const unsigned char* __restrict__ Bp,
            const float* __restrict__ scale, const float* __restrict__ pts,
            const int* __restrict__ glist, float* __restrict__ out)
{
    const int t    = threadIdx.x;
    const int lane = t & 63;
    const int wid  = t >> 6;       // 0..7
    const int wr   = wid >> 2;     // 0..1  (M split: 128 rows)
    const int wc   = wid & 3;      // 0..3  (N split: 64 cols)

    // XCD swizzle (512 % 8 == 0 -> bijective); XCD x owns group x's A slab.
    const int nwg  = gridDim.x;
    const int cpx  = nwg >> 3;
    const int bid  = blockIdx.x;
    const int swzb = (bid & 7) * cpx + (bid >> 3);
    const int mtc  = swzb >> 4;    // 0..31
    const int ntc  = swzb & 15;    // 0..15
    const int brow = mtc * BM;
    const int bcol = ntc * BN;

    int g = 0;
    #pragma unroll
    for (int i = 0; i < NG - 1; ++i)
        if (brow >= glist[i]) g = i + 1;

    const unsigned char* abase = Ap;
    const unsigned char* bbase = Bp + (size_t)g * B_FRAGS_PER_G * FROW_BYTES;

    // per-lane fragment offsets (advance kt by +1024 on the base)
    int aoff[8], boff[4];
    #pragma unroll
    for (int m = 0; m < 8; ++m)
        aoff[m] = (mtc * 16 + wr * 8 + m) * FROW_BYTES + lane * 16;
    #pragma unroll
    for (int n = 0; n < 4; ++n)
        boff[n] = (ntc * 16 + wc * 4 + n) * FROW_BYTES + lane * 16;

    v4i acc[8][4];
    #pragma unroll
    for (int i = 0; i < 8; ++i)
        #pragma unroll
        for (int j = 0; j < 4; ++j)
            acc[i][j] = (v4i){0, 0, 0, 0};

    v4i afc[8], bfc[4], afn[8], bfn[4];

    // prologue: kt=0 fragments
    #pragma unroll
    for (int n = 0; n < 4; ++n) bfc[n] = *(const v4i*)(bbase + boff[n]);
    #pragma unroll
    for (int m = 0; m < 8; ++m) afc[m] = *(const v4i*)(abase + aoff[m]);

    #pragma unroll 1
    for (int it = 0; it < NKT / 2; ++it) {
        // consume kt=2it, prefetch kt=2it+1 (always exists)
        KSTEP(afc, bfc, afn, bfn, FRAG_BYTES, true);
        // consume kt=2it+1, prefetch kt=2it+2 (except last)
        const bool pf2 = (it < NKT / 2 - 1);
        KSTEP(afn, bfn, afc, bfc, 2 * FRAG_BYTES, pf2);
        abase += 2 * FRAG_BYTES;
        bbase += 2 * FRAG_BYTES;
    }

    // ---- epilogue: dequant + store (verified 16x16 C/D map) ----
    #pragma unroll
    for (int mi = 0; mi < 8; ++mi) {
        const int r0 = brow + wr * 128 + mi * 16 + (lane >> 4) * 4;
        float pt[4];
        #pragma unroll
        for (int e = 0; e < 4; ++e) pt[e] = pts[r0 + e];
        #pragma unroll
        for (int ni = 0; ni < 4; ++ni) {
            const int col = bcol + wc * 64 + ni * 16 + (lane & 15);
            const float sc = scale[g * NN + col];
            #pragma unroll
            for (int e = 0; e < 4; ++e)
                out[(size_t)(r0 + e) * NN + col] = (float)acc[mi][ni][e] * sc * pt[e];
        }
    }
}

// ---- fused fallback (only if ws too small; round-1 verified kernel) ----
__global__ __launch_bounds__(256, 2)
void gg_i8(const int* __restrict__ A, const int* __restrict__ B,
           const float* __restrict__ scale, const float* __restrict__ pts,
           const int* __restrict__ glist, float* __restrict__ out)
{
    __shared__ unsigned char Ab[2][128 * 64];
    __shared__ unsigned char Bb[2][128 * 64];

    const int t    = threadIdx.x;
    const int lane = t & 63;
    const int wid  = t >> 6;
    const int wr   = wid >> 1;
    const int wc   = wid & 1;

    const int nwg  = gridDim.x;
    const int cpx  = nwg >> 3;
    const int bid  = blockIdx.x;
    const int swzb = (bid & 7) * cpx + (bid >> 3);
    const int mt   = swzb >> 5;
    const int nt   = swzb & 31;
    const int brow = mt * 128;
    const int bcol = nt * 128;

    int g = 0;
    #pragma unroll
    for (int i = 0; i < NG - 1; ++i)
        if (brow >= glist[i]) g = i + 1;
    const int* Bg = B + (size_t)g * (KK * NN);

    const int arow = t >> 4;
    const int acol = (t & 15) * 4;
    const int bkq = (t >> 5) * 8;
    const int bnq = (t & 31) * 4;

    const int* aP = A  + (size_t)(brow + arow) * KK + acol;
    const int* bP = Bg + (size_t)bkq * NN + bcol + bnq;

    int awoff[8];
    #pragma unroll
    for (int i = 0; i < 8; ++i) awoff[i] = swz(arow + i * 16, acol);
    int bwoff[4];
    #pragma unroll
    for (int ni = 0; ni < 4; ++ni) bwoff[ni] = swz(bnq + ni, bkq);

    const int fr = lane & 15;
    const int kh = lane >> 4;
    int afoff[4], bfoff[4];
    #pragma unroll
    for (int mi = 0; mi < 4; ++mi) afoff[mi] = swz(wr * 64 + mi * 16 + fr, kh * 16);
    #pragma unroll
    for (int ni = 0; ni < 4; ++ni) bfoff[ni] = swz(wc * 64 + ni * 16 + fr, kh * 16);

    v4i aL[8], bL[8];
    v4i acc[4][4];
    #pragma unroll
    for (int i = 0; i < 4; ++i)
        #pragma unroll
        for (int j = 0; j < 4; ++j)
            acc[i][j] = (v4i){0, 0, 0, 0};

    auto stage_load = [&](int kt) {
        const int* ap = aP + kt * 64;
        #pragma unroll
        for (int i = 0; i < 8; ++i)
            aL[i] = *(const v4i*)(ap + (size_t)i * 16 * KK);
        const int* bp = bP + (size_t)kt * 64 * NN;
        #pragma unroll
        for (int j = 0; j < 8; ++j)
            bL[j] = *(const v4i*)(bp + (size_t)j * NN);
    };

    auto stage_write = [&](int buf) {
        #pragma unroll
        for (int i = 0; i < 8; ++i)
            *(unsigned*)(&Ab[buf][awoff[i]]) = pack4(aL[i]);
        #pragma unroll
        for (int ni = 0; ni < 4; ++ni) {
            unsigned lo = (bL[0][ni] & 255) | ((bL[1][ni] & 255) << 8) |
                          ((bL[2][ni] & 255) << 16) | ((unsigned)bL[3][ni] << 24);
            unsigned hi = (bL[4][ni] & 255) | ((bL[5][ni] & 255) << 8) |
                          ((bL[6][ni] & 255) << 16) | ((unsigned)bL[7][ni] << 24);
            unsigned long long w = (unsigned long long)lo |
                                   ((unsigned long long)hi << 32);
            *(unsigned long long*)(&Bb[buf][bwoff[ni]]) = w;
        }
    };

    stage_load(0);
    stage_write(0);
    __syncthreads();

    int cur = 0;
    for (int kt = 0; kt < NKT; ++kt) {
        const bool pf = (kt + 1 < NKT);
        if (pf) stage_load(kt + 1);

        v4i af[4], bfr[4];
        #pragma unroll
        for (int mi = 0; mi < 4; ++mi)
            af[mi] = *(const v4i*)(&Ab[cur][afoff[mi]]);
        #pragma unroll
        for (int ni = 0; ni < 4; ++ni)
            bfr[ni] = *(const v4i*)(&Bb[cur][bfoff[ni]]);

        #pragma unroll
        for (int mi = 0; mi < 4; ++mi)
            #pragma unroll
            for (int ni = 0; ni < 4; ++ni)
                acc[mi][ni] = __builtin_amdgcn_mfma_i32_16x16x64_i8(
                    af[mi], bfr[ni], acc[mi][ni], 0, 0, 0);

        if (pf) stage_write(cur ^ 1);
        __syncthreads();
        cur ^= 1;
    }

    #pragma unroll
    for (int mi = 0; mi < 4; ++mi) {
        const int r0 = brow + wr * 64 + mi * 16 + (lane >> 4) * 4;
        #pragma unroll
        for (int ni = 0; ni < 4; ++ni) {
            const int col = bcol + wc * 64 + ni * 16 + (lane & 15);
            const float sc = scale[g * NN + col];
            #pragma unroll
            for (int e = 0; e < 4; ++e) {
                const int r = r0 + e;
                out[(size_t)r * NN + col] = (float)acc[mi][ni][e] * sc * pts[r];
            }
        }
    }
}

extern "C" void kernel_launch(void* const* d_in, const int* in_sizes, int n_in,
                              void* d_out, int out_size, void* d_ws, size_t ws_size,
                              hipStream_t stream) {
    const int*   A     = (const int*)d_in[0];
    const int*   B     = (const int*)d_in[1];
    const float* scale = (const float*)d_in[2];
    const float* pts   = (const float*)d_in[3];
    const int*   glist = (const int*)d_in[4];
    float*       out   = (float*)d_out;

    if (ws_size >= AP_BYTES + BP_BYTES) {
        unsigned char* Ap = (unsigned char*)d_ws;
        unsigned char* Bp = Ap + AP_BYTES;
        pack_a<<<dim3(A_FRAGS), 256, 0, stream>>>(A, Ap);
        pack_b<<<dim3(NG * 32 * NKT), 256, 0, stream>>>(B, Bp);
        gg_i8r<<<dim3((MM / BM) * (NN / BN)), 512, 0, stream>>>(
            Ap, Bp, scale, pts, glist, out);
    } else {
        gg_i8<<<dim3((MM / 128) * (NN / 128)), 256, 0, stream>>>(
            A, B, scale, pts, glist, out);
    }
}